// Round 7
// baseline (132.620 us; speedup 1.0000x reference)
//
#include <hip/hip_runtime.h>

typedef __bf16 bf16x8 __attribute__((ext_vector_type(8)));
typedef float f32x4 __attribute__((ext_vector_type(4)));

#define HH 64
#define WW 64
#define HW 4096
#define COUT 256
#define NROWS 12      // staged input rows [rowbase, rowbase+11]
#define XROW 65       // px slots per staged row (odd stride)
#define XS_OFF 32768  // Xs after 32 KB Bs ring
#define XSBUF 12480   // one Xs buffer: 12*65*8ch*2B

// Raw barrier: flush LDS (lgkmcnt) but do NOT drain vmcnt — staging global
// loads stay in flight across the barrier (compiler waits at their uses).
__device__ __forceinline__ void bar_sync() {
    asm volatile("s_waitcnt lgkmcnt(0)" ::: "memory");
    __builtin_amdgcn_s_barrier();
    asm volatile("" ::: "memory");
}

// ---------------------------------------------------------------------------
// Kernel 1: blend circle weights -> bf16, A layout by 8-K blocks:
// K = g*72 + tap*8 + j  (g = 8-ch group 0..31, tap 0..8, j = ch&7)
// kb = g*9 + tap = K/8.  Frag for (kb, tm=o/16, rr=o&15) = 16 B at
// wp[(kb*256 + tm*16 + rr)*8].  Block = one kb (tap block-uniform).
// ---------------------------------------------------------------------------
__global__ __launch_bounds__(256) void prep_weights(const float* __restrict__ weight,
                                                    __bf16* __restrict__ wp) {
    const int kb  = blockIdx.x;            // 0..287
    const int tid = threadIdx.x;
    const int tap = kb % 9;
    const int g   = kb / 9;
    const int rr  = tid & 15;
    const int tm  = tid >> 4;
    const int o   = tm * 16 + rr;
    const float* wb = weight + ((size_t)o * 256 + g * 8) * 9;
    const float Af = 0.70710678118654752f;
    const float Bf = 1.0f - Af;
    bf16x8 v;
    #pragma unroll
    for (int j = 0; j < 8; ++j) {
        const float* w = wb + j * 9;
        float r;
        switch (tap) {
            case 0:  r = Af*(Af*w[0]+Bf*w[1]) + Bf*(Af*w[3]+Bf*w[4]); break;
            case 1:  r = w[1]; break;
            case 2:  r = Af*(Bf*w[1]+Af*w[2]) + Bf*(Bf*w[4]+Af*w[5]); break;
            case 3:  r = w[3]; break;
            case 4:  r = w[4]; break;
            case 5:  r = w[5]; break;
            case 6:  r = Bf*(Af*w[3]+Bf*w[4]) + Af*(Af*w[6]+Bf*w[7]); break;
            case 7:  r = w[7]; break;
            default: r = Bf*(Bf*w[4]+Af*w[5]) + Af*(Bf*w[7]+Af*w[8]); break;
        }
        v[j] = (__bf16)r;
    }
    *(bf16x8*)&wp[((size_t)kb * 256 + tid) * 8] = v;
}

// ---------------------------------------------------------------------------
// Kernel 2: single-barrier-per-stage pipelined sample + implicit GEMM.
// 256 blocks x 512 thr (8 waves, 1 block/CU). Tile M=256 x N=64.
// 8-ch stages s=0..33: [bar] write Xs[s&1](group s) | load R(group s+1) |
// gather group s-1 -> Bs ring | MFMA watermarked ksteps.  Bs ring = 256
// K-cols x 64 px, XOR-swizzled (col ^ ((px&7)<<3)) -> conflict-free wr/rd.
// Wave = (mg 0..3, k-parity): acc[4][4], epilogue LDS reduce (R6-proven).
// ---------------------------------------------------------------------------
__global__ __launch_bounds__(512, 2) void dcn_main(
        const float* __restrict__ x, const float* __restrict__ off,
        const float* __restrict__ msk, const __bf16* __restrict__ wp,
        const float* __restrict__ bias, float* __restrict__ out) {
    __shared__ char smem[65536];   // Bs[0..32767] | Xs0/Xs1; epilogue: f32 scr

    const int tid  = threadIdx.x;
    const int wv   = tid >> 6;
    const int lane = tid & 63;
    const int q    = lane >> 4, rr = lane & 15;
    const int px   = lane;                 // sampling pixel column

    const int mg  = wv & 3;
    const int klp = wv >> 2;               // k-parity for MFMA split

    const int bid = blockIdx.x;
    const int xcd = bid & 7;
    const int b   = xcd >> 1;
    const int h   = ((xcd & 1) << 5) | (bid >> 3);

    const int rowbase = min(max(h - 5, 0), HH - NROWS);
    const float* xb = x + (size_t)b * 256 * HW;

    // ---- staging slots: slotA = (row=wv, px=lane); slotB (wv<4): row=8+wv --
    const int GOFF_A = (rowbase + wv) * 64 + lane;
    const int GOFF_B = (rowbase + 8 + wv) * 64 + lane;
    const int XA_A   = (wv * XROW + lane) * 16;         // byte offs in Xs buf
    const int XA_B   = ((8 + wv) * XROW + lane) * 16;
    const bool hasB  = (wv < 4);

    // ---- gather-unit params, computed ONCE --------------------------------
    // k=0: tap = wv (all waves); k=1: tap = 8 (wave 0 only).
    float W00[2], W01[2], W10[2], W11[2];
    int AY0[2], AY1[2], DXO[2], TAP8[2], GP[2];
    const bool UV1 = (wv == 0);
    #pragma unroll
    for (int k = 0; k < 2; ++k) {
        if (k == 0 || UV1) {
            int tap = (k == 0) ? wv : 8;
            int ki = tap / 3, kj = tap - 3 * ki;
            const float* offp = off + (size_t)b * 18 * HW + h * 64 + px;
            float dy = offp[(2 * tap) * HW];
            float dx = offp[(2 * tap + 1) * HW];
            float mv = msk[(size_t)b * 9 * HW + (size_t)tap * HW + h * 64 + px];
            float py  = (float)(h - 1 + ki) + dy;
            float pxf = (float)(px - 1 + kj) + dx;
            float y0f = floorf(py), x0f = floorf(pxf);
            float ly = py - y0f, lx = pxf - x0f;
            float hy = 1.0f - ly, hx = 1.0f - lx;
            int y0 = (int)y0f, x0 = (int)x0f;
            int y1 = y0 + 1, x1 = x0 + 1;
            bool vy0 = (y0 >= 0) && (y0 < HH), vy1 = (y1 >= 0) && (y1 < HH);
            bool vx0 = (x0 >= 0) && (x0 < WW), vx1 = (x1 >= 0) && (x1 < WW);
            int cy0 = min(max(y0, 0), HH - 1), cy1 = min(max(y1, 0), HH - 1);
            int cx0 = min(max(x0, 0), WW - 1), cx1 = min(max(x1, 0), WW - 1);
            W00[k] = (vy0 && vx0) ? hy * hx * mv : 0.0f;
            W01[k] = (vy0 && vx1) ? hy * lx * mv : 0.0f;
            W10[k] = (vy1 && vx0) ? ly * hx * mv : 0.0f;
            W11[k] = (vy1 && vx1) ? ly * lx * mv : 0.0f;
            int ry0 = min(max(cy0 - rowbase, 0), NROWS - 1);
            int ry1 = min(max(cy1 - rowbase, 0), NROWS - 1);
            bool useG = (vy0 && (cy0 < rowbase || cy0 > rowbase + NROWS - 1))
                     || (vy1 && (cy1 < rowbase || cy1 > rowbase + NROWS - 1));
            AY0[k]  = (ry0 * XROW + cx0) * 16;
            AY1[k]  = (ry1 * XROW + cx0) * 16;
            DXO[k]  = (cx1 - cx0) * 16;
            TAP8[k] = tap * 8;
            GP[k]   = cy0 | (cy1 << 6) | (cx0 << 12) | (cx1 << 18)
                    | (useG ? (1u << 31) : 0);
        }
    }

    f32x4 acc[4][4];
    #pragma unroll
    for (int i = 0; i < 4; ++i)
        #pragma unroll
        for (int n = 0; n < 4; ++n)
            acc[i][n] = (f32x4)0.0f;

    // ---- preload staging regs for group 0 ---------------------------------
    float R[2][8];
    {
        const float* pA = xb + GOFF_A;
        #pragma unroll
        for (int j = 0; j < 8; ++j) R[0][j] = pA[j * HW];
        if (hasB) {
            const float* pB = xb + GOFF_B;
            #pragma unroll
            for (int j = 0; j < 8; ++j) R[1][j] = pB[j * HW];
        }
    }

    // ---- preload A frags for this wave's first kstep (= klp) --------------
    const char* wpB = (const char*)wp;
    const char* ap = wpB + (size_t)(4 * klp + q) * 4096 + mg * 1024 + rr * 16;
    bf16x8 a0 = *(const bf16x8*)ap;
    bf16x8 a1 = *(const bf16x8*)(ap + 256);
    bf16x8 a2 = *(const bf16x8*)(ap + 512);
    bf16x8 a3 = *(const bf16x8*)(ap + 768);
    int kwp = klp;

    const int sw8 = (lane & 7) << 3;      // XOR swizzle key (px = lane)

    #pragma unroll 1
    for (int s = 0; s <= 33; ++s) {
        bar_sync();
        // ---- write Xs[s&1] (group s) from regs ----------------------------
        if (s < 32) {
            char* xw = smem + XS_OFF + (s & 1) * XSBUF;
            bf16x8 vA;
            #pragma unroll
            for (int j = 0; j < 8; ++j) vA[j] = (__bf16)R[0][j];
            *(bf16x8*)(xw + XA_A) = vA;
            if (hasB) {
                bf16x8 vB;
                #pragma unroll
                for (int j = 0; j < 8; ++j) vB[j] = (__bf16)R[1][j];
                *(bf16x8*)(xw + XA_B) = vB;
            }
        }
        // ---- issue group s+1 global loads (stay in flight) ----------------
        if (s < 31) {
            const float* pA = xb + (size_t)((s + 1) * 8) * HW + GOFF_A;
            #pragma unroll
            for (int j = 0; j < 8; ++j) R[0][j] = pA[j * HW];
            if (hasB) {
                const float* pB = xb + (size_t)((s + 1) * 8) * HW + GOFF_B;
                #pragma unroll
                for (int j = 0; j < 8; ++j) R[1][j] = pB[j * HW];
            }
        }
        // ---- gather group s-1 from Xs[(s-1)&1] -> Bs ring -----------------
        if (s >= 1 && s <= 32) {
            const int g = s - 1;
            const char* xr = smem + XS_OFF + (g & 1) * XSBUF;
            const int gb8 = (g * 72) & 255;
            #pragma unroll
            for (int k = 0; k < 2; ++k) {
                if (k == 0 || UV1) {
                    bf16x8 c00 = *(const bf16x8*)(xr + AY0[k]);
                    bf16x8 c01 = *(const bf16x8*)(xr + AY0[k] + DXO[k]);
                    bf16x8 c10 = *(const bf16x8*)(xr + AY1[k]);
                    bf16x8 c11 = *(const bf16x8*)(xr + AY1[k] + DXO[k]);
                    float w0 = W00[k], w1 = W01[k], w2 = W10[k], w3 = W11[k];
                    bf16x8 res;
                    #pragma unroll
                    for (int j = 0; j < 8; ++j) {
                        float v = w0 * (float)c00[j] + w1 * (float)c01[j]
                                + w2 * (float)c10[j] + w3 * (float)c11[j];
                        res[j] = (__bf16)v;
                    }
                    int gp = GP[k];
                    if (gp < 0) {   // rare: valid corner outside staged rows
                        int cy0 = gp & 63, cy1 = (gp >> 6) & 63;
                        int cx0 = (gp >> 12) & 63, cx1 = (gp >> 18) & 63;
                        const float* xc = xb + (size_t)(g * 8) * HW;
                        int i00 = cy0 * 64 + cx0, i01 = cy0 * 64 + cx1;
                        int i10 = cy1 * 64 + cx0, i11 = cy1 * 64 + cx1;
                        #pragma unroll
                        for (int j = 0; j < 8; ++j) {
                            float v = w0 * xc[i00] + w1 * xc[i01]
                                    + w2 * xc[i10] + w3 * xc[i11];
                            res[j] = (__bf16)v;
                            xc += HW;
                        }
                    }
                    const int colp = ((gb8 + TAP8[k]) & 255) ^ sw8;
                    *(bf16x8*)(smem + lane * 512 + colp * 2) = res;
                }
            }
        }
        // ---- MFMA: watermarked ksteps, k-parity split ---------------------
        int k1 = (s >= 2) ? ((72 * (s - 1)) >> 5) : 0;
        if (k1 > 72) k1 = 72;
        while (kwp < k1) {
            bf16x8 n0 = a0, n1 = a1, n2 = a2, n3 = a3;
            if (kwp + 2 < 72) {
                const char* np = ap + 32768;
                n0 = *(const bf16x8*)np;
                n1 = *(const bf16x8*)(np + 256);
                n2 = *(const bf16x8*)(np + 512);
                n3 = *(const bf16x8*)(np + 768);
            }
            const int col2 = ((((kwp << 5) + (q << 3)) & 255) ^ ((rr & 7) << 3)) * 2;
            const char* bp = smem + rr * 512 + col2;
            bf16x8 bb0 = *(const bf16x8*)(bp);
            bf16x8 bb1 = *(const bf16x8*)(bp + 16 * 512);
            bf16x8 bb2 = *(const bf16x8*)(bp + 32 * 512);
            bf16x8 bb3 = *(const bf16x8*)(bp + 48 * 512);
            acc[0][0] = __builtin_amdgcn_mfma_f32_16x16x32_bf16(a0, bb0, acc[0][0], 0, 0, 0);
            acc[1][0] = __builtin_amdgcn_mfma_f32_16x16x32_bf16(a1, bb0, acc[1][0], 0, 0, 0);
            acc[2][0] = __builtin_amdgcn_mfma_f32_16x16x32_bf16(a2, bb0, acc[2][0], 0, 0, 0);
            acc[3][0] = __builtin_amdgcn_mfma_f32_16x16x32_bf16(a3, bb0, acc[3][0], 0, 0, 0);
            acc[0][1] = __builtin_amdgcn_mfma_f32_16x16x32_bf16(a0, bb1, acc[0][1], 0, 0, 0);
            acc[1][1] = __builtin_amdgcn_mfma_f32_16x16x32_bf16(a1, bb1, acc[1][1], 0, 0, 0);
            acc[2][1] = __builtin_amdgcn_mfma_f32_16x16x32_bf16(a2, bb1, acc[2][1], 0, 0, 0);
            acc[3][1] = __builtin_amdgcn_mfma_f32_16x16x32_bf16(a3, bb1, acc[3][1], 0, 0, 0);
            acc[0][2] = __builtin_amdgcn_mfma_f32_16x16x32_bf16(a0, bb2, acc[0][2], 0, 0, 0);
            acc[1][2] = __builtin_amdgcn_mfma_f32_16x16x32_bf16(a1, bb2, acc[1][2], 0, 0, 0);
            acc[2][2] = __builtin_amdgcn_mfma_f32_16x16x32_bf16(a2, bb2, acc[2][2], 0, 0, 0);
            acc[3][2] = __builtin_amdgcn_mfma_f32_16x16x32_bf16(a3, bb2, acc[3][2], 0, 0, 0);
            acc[0][3] = __builtin_amdgcn_mfma_f32_16x16x32_bf16(a0, bb3, acc[0][3], 0, 0, 0);
            acc[1][3] = __builtin_amdgcn_mfma_f32_16x16x32_bf16(a1, bb3, acc[1][3], 0, 0, 0);
            acc[2][3] = __builtin_amdgcn_mfma_f32_16x16x32_bf16(a2, bb3, acc[2][3], 0, 0, 0);
            acc[3][3] = __builtin_amdgcn_mfma_f32_16x16x32_bf16(a3, bb3, acc[3][3], 0, 0, 0);
            ap += 32768;
            kwp += 2;
            a0 = n0; a1 = n1; a2 = n2; a3 = n3;
        }
    }

    // ---- epilogue: cross-wave parity-partial reduce via LDS, then store ---
    float* scr = (float*)smem;   // Bs/Xs dead now
    bar_sync();
    if (wv >= 4) {
        const int base = (wv - 4) * 4096 + lane * 4;
        #pragma unroll
        for (int i = 0; i < 4; ++i)
            #pragma unroll
            for (int n = 0; n < 4; ++n)
                *(f32x4*)&scr[base + (i * 4 + n) * 256] = acc[i][n];
    }
    bar_sync();
    if (wv < 4) {
        const int mrow = wv * 64;
        const int base = wv * 4096 + lane * 4;
        #pragma unroll
        for (int i = 0; i < 4; ++i) {
            #pragma unroll
            for (int n = 0; n < 4; ++n) {
                f32x4 p = *(const f32x4*)&scr[base + (i * 4 + n) * 256];
                #pragma unroll
                for (int e = 0; e < 4; ++e) {
                    int m = mrow + i * 16 + q * 4 + e;
                    out[((size_t)b * COUT + m) * HW + h * 64 + n * 16 + rr]
                        = acc[i][n][e] + p[e] + bias[m];
                }
            }
        }
    }
}

extern "C" void kernel_launch(void* const* d_in, const int* in_sizes, int n_in,
                              void* d_out, int out_size, void* d_ws, size_t ws_size,
                              hipStream_t stream) {
    const float* x      = (const float*)d_in[0];   // [4,256,64,64]
    const float* off    = (const float*)d_in[1];   // [4,18,64,64]
    const float* msk    = (const float*)d_in[2];   // [4,9,64,64]
    const float* weight = (const float*)d_in[3];   // [256,256,3,3]
    const float* bias   = (const float*)d_in[4];   // [256]
    float* out = (float*)d_out;                    // [4,256,64,64]

    __bf16* wp = (__bf16*)d_ws;                    // 589824 bf16 = 1.18 MB

    prep_weights<<<288, 256, 0, stream>>>(weight, wp);
    dcn_main<<<256, 512, 0, stream>>>(x, off, msk, wp, bias, out);
}